// Round 1
// baseline (131.372 us; speedup 1.0000x reference)
//
#include <hip/hip_runtime.h>
#include <hip/hip_bf16.h>

// ---------------------------------------------------------------------------
// k1[z,i,j] = sum_{y,w} Q[i,j,y,w] * Ysh[z,y] * Rad[z,w]
//  => GEMM: P[z, k] @ Qmat[k, c],  k = y*96+w (K=864), c = i*16+j (256)
// Rad(t) is piecewise-linear in t=|r| (relu MLP with scalar input) =>
// precompute per-interval (A,B) tables: Rad_w = A[iv][w]*t + B[iv][w].
// ---------------------------------------------------------------------------

typedef __attribute__((ext_vector_type(8)))  short bfrag;   // 8 x bf16 (4 VGPR)
typedef __attribute__((ext_vector_type(16))) float fx16;    // 32x32 accum

// workspace byte offsets
#define WS_TB 0        // 128 f32 sorted breakpoints (+inf pad)
#define WS_AT 512      // 129*96 f32
#define WS_BT 50048    // 129*96 f32
#define WS_QP 99584    // 27*4*256*8 bf16 = 442368 B packed Q
// total 541952 B

__device__ inline unsigned short f2bf(float f) {   // RNE float->bf16
  union { float f; unsigned int u; } v; v.f = f;
  unsigned int r = v.u + 0x7FFFu + ((v.u >> 16) & 1u);
  return (unsigned short)(r >> 16);
}
__device__ inline unsigned int pack2(float a, float b) {
  return (unsigned int)f2bf(a) | ((unsigned int)f2bf(b) << 16);
}

__device__ inline void gl_lds16(const void* g, void* l) {
  // async global->LDS, 16B/lane; LDS dest = wave-uniform base + lane*16
  __builtin_amdgcn_global_load_lds(
      (const __attribute__((address_space(1))) unsigned int*)g,
      (__attribute__((address_space(3))) unsigned int*)l, 16, 0, 0);
}

// ---------------------------------------------------------------------------
// Kernel 1: piecewise-linear tables for Rad(t). One block, 128 threads.
// ---------------------------------------------------------------------------
__global__ void k_tables(const float* __restrict__ W1, const float* __restrict__ b1,
                         const float* __restrict__ W2, const float* __restrict__ b2,
                         float* __restrict__ tb, float* __restrict__ At,
                         float* __restrict__ Bt) {
  __shared__ float val_s[128], stb_s[128], w1_s[128], b1_s[128];
  __shared__ int   perm_s[128];
  const float INF = __builtin_inff();
  int t = threadIdx.x;
  float w1 = W1[t], b1v = b1[t];
  w1_s[t] = w1; b1_s[t] = b1v;
  float tj = -b1v / w1;                       // hinge location
  bool valid = (w1 != 0.0f) && (tj > 0.0f);   // only t>0 matters (t = radius)
  val_s[t] = valid ? tj : INF;
  __syncthreads();
  // O(n^2) rank sort (stable)
  float v = val_s[t];
  int rank = 0;
  for (int m = 0; m < 128; ++m) {
    float vm = val_s[m];
    rank += (vm < v || (vm == v && m < t)) ? 1 : 0;
  }
  stb_s[rank] = v; perm_s[rank] = t;
  __syncthreads();
  tb[t] = stb_s[t];
  if (t < 96) {
    // interval 0: activity at a midpoint below the first breakpoint
    float s0  = stb_s[0];
    float tm0 = (s0 == INF) ? 1.0f : 0.5f * s0;
    float sa = 0.f, sb = 0.f;
    for (int j = 0; j < 128; ++j) {
      if (tm0 * w1_s[j] + b1_s[j] > 0.0f) {
        float w2 = W2[j * 96 + t];
        sa += w2 * w1_s[j]; sb += w2 * b1_s[j];
      }
    }
    float b2v = b2[t];
    At[t] = sa; Bt[t] = sb + b2v;
    // walk breakpoints ascending; exactly one hinge toggles per breakpoint
    for (int s = 0; s < 128; ++s) {
      if (stb_s[s] < INF) {
        int j = perm_s[s];
        float w2 = W2[j * 96 + t];
        if (w1_s[j] > 0.f) { sa += w2 * w1_s[j]; sb += w2 * b1_s[j]; }  // activates
        else               { sa -= w2 * w1_s[j]; sb -= w2 * b1_s[j]; }  // deactivates
      }
      At[(s + 1) * 96 + t] = sa; Bt[(s + 1) * 96 + t] = sb + b2v;
    }
  }
}

// ---------------------------------------------------------------------------
// Kernel 2: Q (c-major [256][864] f32) -> bf16 packed for B-fragments.
// Layout: [kc(27)][q(4)][c(256)][e(8)], q = ks*2 + half, k = kc*32+ks*16+half*8+e
// B-frag read (chunk kc): lane reads 16B at ((ks*2 + lane>>5)*256 + c)*16.
// ---------------------------------------------------------------------------
__global__ void k_qpack(const float* __restrict__ Q, unsigned short* __restrict__ qp) {
  int t = blockIdx.x * 256 + threadIdx.x;          // < 221184
  int e  = t & 7;
  int c  = (t >> 3) & 255;
  int q  = (t >> 11) & 3;
  int kc = t >> 13;
  int k  = kc * 32 + (q >> 1) * 16 + (q & 1) * 8 + e;
  qp[t] = f2bf(Q[c * 864 + k]);
}

// ---------------------------------------------------------------------------
// Kernel 3: fused P-build + GEMM. Block = 64 points x 256 cols, 4 waves,
// wave tile 64x64 via 2x2 frags of mfma_f32_32x32x16_bf16, BK=32, Q dbuf.
// ---------------------------------------------------------------------------
#define PSTR 872  // 864 + 8 pad: row stride 1744B, 16B-aligned, bank-spread

__global__ __launch_bounds__(256, 1)
void k_main(const float* __restrict__ r, const float* __restrict__ tbg,
            const float* __restrict__ At, const float* __restrict__ Bt,
            const unsigned short* __restrict__ qp, const float* __restrict__ K0,
            float* __restrict__ out) {
  __shared__ unsigned short P_s[64][PSTR];   // 111,616 B
  __shared__ unsigned short Qb[2][8192];     //  32,768 B (2 x 16KB chunks)
  __shared__ float tb_s[128];
  __shared__ float radii_s[64];

  const int tid  = threadIdx.x;
  const int lane = tid & 63;
  const int wave = tid >> 6;
  const int hl   = lane >> 5;
  const int l31  = lane & 31;
  const int z0   = blockIdx.x * 64;
  const char* qg = (const char*)qp;

  // issue async stage of Q chunk 0 immediately (overlaps phase 1)
  {
    const char* g = qg + wave * 4096 + lane * 16;
    char* l = ((char*)&Qb[0][0]) + wave * 4096;
#pragma unroll
    for (int i = 0; i < 4; ++i) gl_lds16(g + i * 1024, l + i * 1024);
  }
  if (tid < 128) tb_s[tid] = tbg[tid];
  __syncthreads();

  // ---------------- phase 1: build P tile (4 threads per point) ------------
  {
    const int zloc = tid >> 2, wq = tid & 3;
    const int z = z0 + zloc;
    float rx = r[z * 3 + 0], ry = r[z * 3 + 1], rz = r[z * 3 + 2];
    float radii = sqrtf(rx * rx + ry * ry + rz * rz);
    if (wq == 0) radii_s[zloc] = radii;
    float inv = (radii > 0.f) ? (1.0f / radii) : 1.0f;  // = 1/safe
    float x = rx * inv, y = ry * inv, zc = rz * inv;
    const float SQ3 = 1.7320508075688772f, SQ5 = 2.2360679774997896f,
                SQ15 = 3.872983346207417f;
    float Y[9];
    Y[0] = 1.f;        Y[1] = SQ3 * y;   Y[2] = SQ3 * zc;  Y[3] = SQ3 * x;
    Y[4] = SQ15 * x * y; Y[5] = SQ15 * y * zc;
    Y[6] = 0.5f * SQ5 * (3.f * zc * zc - 1.f);
    Y[7] = SQ15 * x * zc; Y[8] = 0.5f * SQ15 * (x * x - y * y);
    // interval lookup: iv = #{breakpoints < radii}
    int lo = 0, hi = 128;
    while (lo < hi) { int mid = (lo + hi) >> 1;
                      if (tb_s[mid] < radii) lo = mid + 1; else hi = mid; }
    const int iv = lo, w0 = wq * 24;
    float av[24], bv[24], rv[24];
    const float4* Ar = (const float4*)(At + iv * 96 + w0);
    const float4* Br = (const float4*)(Bt + iv * 96 + w0);
#pragma unroll
    for (int g = 0; g < 6; ++g) {
      float4 a = Ar[g], b = Br[g];
      av[g*4+0]=a.x; av[g*4+1]=a.y; av[g*4+2]=a.z; av[g*4+3]=a.w;
      bv[g*4+0]=b.x; bv[g*4+1]=b.y; bv[g*4+2]=b.z; bv[g*4+3]=b.w;
    }
#pragma unroll
    for (int m = 0; m < 24; ++m) rv[m] = fmaf(av[m], radii, bv[m]);  // Rad_w
#pragma unroll
    for (int yi = 0; yi < 9; ++yi) {
      float yv = Y[yi];
#pragma unroll
      for (int g = 0; g < 3; ++g) {
        uint4 pk;
        pk.x = pack2(yv * rv[g*8+0], yv * rv[g*8+1]);
        pk.y = pack2(yv * rv[g*8+2], yv * rv[g*8+3]);
        pk.z = pack2(yv * rv[g*8+4], yv * rv[g*8+5]);
        pk.w = pack2(yv * rv[g*8+6], yv * rv[g*8+7]);
        *(uint4*)(&P_s[zloc][yi * 96 + w0 + g * 8]) = pk;
      }
    }
  }
  __syncthreads();   // P visible; stage(0) drained (syncthreads waits vmcnt)

  // ---------------- phase 2: K-loop GEMM -----------------------------------
  const int c0w = wave * 64;
  fx16 acc00, acc01, acc10, acc11;
#pragma unroll
  for (int i = 0; i < 16; ++i) { acc00[i]=0.f; acc01[i]=0.f; acc10[i]=0.f; acc11[i]=0.f; }

  int buf = 0;
  for (int kc = 0; kc < 27; ++kc) {
    if (kc + 1 < 27) {   // prefetch next chunk into the other buffer
      const char* g = qg + (kc + 1) * 16384 + wave * 4096 + lane * 16;
      char* l = ((char*)&Qb[buf ^ 1][0]) + wave * 4096;
#pragma unroll
      for (int i = 0; i < 4; ++i) gl_lds16(g + i * 1024, l + i * 1024);
    }
#pragma unroll
    for (int ks = 0; ks < 2; ++ks) {
      const int ka = kc * 32 + ks * 16 + hl * 8;
      bfrag a0 = *(const bfrag*)(&P_s[l31][ka]);
      bfrag a1 = *(const bfrag*)(&P_s[32 + l31][ka]);
      const int qb = ((ks * 2 + hl) * 256 + c0w) * 8;
      bfrag b0 = *(const bfrag*)(&Qb[buf][qb + l31 * 8]);
      bfrag b1 = *(const bfrag*)(&Qb[buf][qb + (32 + l31) * 8]);
      acc00 = __builtin_amdgcn_mfma_f32_32x32x16_bf16(a0, b0, acc00, 0, 0, 0);
      acc01 = __builtin_amdgcn_mfma_f32_32x32x16_bf16(a0, b1, acc01, 0, 0, 0);
      acc10 = __builtin_amdgcn_mfma_f32_32x32x16_bf16(a1, b0, acc10, 0, 0, 0);
      acc11 = __builtin_amdgcn_mfma_f32_32x32x16_bf16(a1, b1, acc11, 0, 0, 0);
    }
    __syncthreads();   // readers done + prefetch landed
    buf ^= 1;
  }

  // ---------------- epilogue: mask-select vs K0, store ---------------------
  const float k0v0 = K0[c0w + l31];
  const float k0v1 = K0[c0w + 32 + l31];
#pragma unroll
  for (int rr = 0; rr < 16; ++rr) {
    const int rbase = (rr & 3) + 8 * (rr >> 2) + 4 * hl;  // C/D row map (m74/m101)
    const int rl0 = rbase, rl1 = rbase + 32;
    const bool m0 = radii_s[rl0] > 0.f;
    const bool m1 = radii_s[rl1] > 0.f;
    const size_t o0 = (size_t)(z0 + rl0) * 256 + c0w + l31;
    const size_t o1 = (size_t)(z0 + rl1) * 256 + c0w + l31;
    out[o0]      = m0 ? acc00[rr] : k0v0;
    out[o0 + 32] = m0 ? acc01[rr] : k0v1;
    out[o1]      = m1 ? acc10[rr] : k0v0;
    out[o1 + 32] = m1 ? acc11[rr] : k0v1;
  }
}

// ---------------------------------------------------------------------------
extern "C" void kernel_launch(void* const* d_in, const int* in_sizes, int n_in,
                              void* d_out, int out_size, void* d_ws, size_t ws_size,
                              hipStream_t stream) {
  const float* r  = (const float*)d_in[0];
  const float* Q  = (const float*)d_in[1];
  const float* W1 = (const float*)d_in[2];
  const float* b1 = (const float*)d_in[3];
  const float* W2 = (const float*)d_in[4];
  const float* b2 = (const float*)d_in[5];
  const float* K0 = (const float*)d_in[6];
  float* out = (float*)d_out;
  char* ws = (char*)d_ws;
  float* tb = (float*)(ws + WS_TB);
  float* At = (float*)(ws + WS_AT);
  float* Bt = (float*)(ws + WS_BT);
  unsigned short* qp = (unsigned short*)(ws + WS_QP);

  hipLaunchKernelGGL(k_tables, dim3(1), dim3(128), 0, stream, W1, b1, W2, b2, tb, At, Bt);
  hipLaunchKernelGGL(k_qpack, dim3(864), dim3(256), 0, stream, Q, qp);
  hipLaunchKernelGGL(k_main, dim3(1024), dim3(256), 0, stream, r, tb, At, Bt, qp, K0, out);
}

// Round 2
// 94.965 us; speedup vs baseline: 1.3834x; 1.3834x over previous
//
#include <hip/hip_runtime.h>
#include <hip/hip_bf16.h>

// ---------------------------------------------------------------------------
// k1[z,i,j] = sum_{y,w} Q[i,j,y,w] * Ysh[z,y] * Rad[z,w]
//  => GEMM: P[z,k] @ Qmat[k,c], k = y*96+w (K=864), c = i*16+j (256)
// P is rank-1 per row: P[z, y*96+w] = Ysh[z,y]*Rad[z,w]. We do NOT materialize
// P: LDS holds Rad (bf16) + Ysh (f32); A-fragments are generated on the fly
// (ds_read_b128 + unpack + mul + v_cvt_pk_bf16_f32). LDS ~80KB => 2 blocks/CU,
// block = 256 rows x 128 cols, 512 blocks = one co-resident round.
// Rad(t) is piecewise-linear in t=|r| (relu MLP, scalar input) => per-interval
// bf16 (A,B) tables: Rad_w = A[iv][w]*t + B[iv][w].  Walls: MFMA 11.6us,
// HBM-write 64MB ~11-15us — design lands both together.
// ---------------------------------------------------------------------------

typedef __attribute__((ext_vector_type(8)))  short bfrag;   // 8 x bf16
typedef __attribute__((ext_vector_type(16))) float fx16;    // 32x32 accum

#define WS_TB  0        // 128 f32 sorted breakpoints (+inf pad)
#define WS_ABT 512      // 129*96 u32 (bf16 A | bf16 B<<16) = 49536 B
#define WS_QP  50048    // 27*4*256*8 bf16 = 442368 B packed Q
// total 492416 B

__device__ inline unsigned short f2bf(float f) {   // RNE float->bf16
  union { float f; unsigned int u; } v; v.f = f;
  unsigned int r = v.u + 0x7FFFu + ((v.u >> 16) & 1u);
  return (unsigned short)(r >> 16);
}
__device__ inline unsigned int pack2(float a, float b) {
  return (unsigned int)f2bf(a) | ((unsigned int)f2bf(b) << 16);
}
__device__ inline float bf_lo(unsigned int v) {
  union { unsigned int u; float f; } c; c.u = v << 16; return c.f;
}
__device__ inline float bf_hi(unsigned int v) {
  union { unsigned int u; float f; } c; c.u = v & 0xFFFF0000u; return c.f;
}
__device__ inline unsigned int cvtpk(float a, float b) {  // D.lo<-bf16(a), D.hi<-bf16(b)
  unsigned int d;
  asm("v_cvt_pk_bf16_f32 %0, %1, %2" : "=v"(d) : "v"(a), "v"(b));
  return d;
}

__device__ inline void gl_lds16(const void* g, void* l) {
  __builtin_amdgcn_global_load_lds(
      (const __attribute__((address_space(1))) unsigned int*)g,
      (__attribute__((address_space(3))) unsigned int*)l, 16, 0, 0);
}

// ---------------------------------------------------------------------------
// Kernel 1: piecewise-linear tables for Rad(t). One block, 128 threads.
// ---------------------------------------------------------------------------
__global__ void k_tables(const float* __restrict__ W1, const float* __restrict__ b1,
                         const float* __restrict__ W2, const float* __restrict__ b2,
                         float* __restrict__ tb, unsigned int* __restrict__ ABt) {
  __shared__ float val_s[128], stb_s[128], w1_s[128], b1_s[128];
  __shared__ int   perm_s[128];
  const float INF = __builtin_inff();
  int t = threadIdx.x;
  float w1 = W1[t], b1v = b1[t];
  w1_s[t] = w1; b1_s[t] = b1v;
  float tj = -b1v / w1;
  bool valid = (w1 != 0.0f) && (tj > 0.0f);
  val_s[t] = valid ? tj : INF;
  __syncthreads();
  float v = val_s[t];
  int rank = 0;
  for (int m = 0; m < 128; ++m) {
    float vm = val_s[m];
    rank += (vm < v || (vm == v && m < t)) ? 1 : 0;
  }
  stb_s[rank] = v; perm_s[rank] = t;
  __syncthreads();
  tb[t] = stb_s[t];
  if (t < 96) {
    float s0  = stb_s[0];
    float tm0 = (s0 == INF) ? 1.0f : 0.5f * s0;
    float sa = 0.f, sb = 0.f;
    for (int j = 0; j < 128; ++j) {
      if (tm0 * w1_s[j] + b1_s[j] > 0.0f) {
        float w2 = W2[j * 96 + t];
        sa += w2 * w1_s[j]; sb += w2 * b1_s[j];
      }
    }
    float b2v = b2[t];
    ABt[t] = pack2(sa, sb + b2v);
    for (int s = 0; s < 128; ++s) {
      if (stb_s[s] < INF) {
        int j = perm_s[s];
        float w2 = W2[j * 96 + t];
        if (w1_s[j] > 0.f) { sa += w2 * w1_s[j]; sb += w2 * b1_s[j]; }
        else               { sa -= w2 * w1_s[j]; sb -= w2 * b1_s[j]; }
      }
      ABt[(s + 1) * 96 + t] = pack2(sa, sb + b2v);
    }
  }
}

// ---------------------------------------------------------------------------
// Kernel 2: Q (c-major [256][864] f32) -> bf16 packed for B-fragments.
// Layout: [kc(27)][q(4)][c(256)][e(8)], q = ks*2 + half, k = kc*32+ks*16+half*8+e
// ---------------------------------------------------------------------------
__global__ void k_qpack(const float* __restrict__ Q, unsigned short* __restrict__ qp) {
  int t = blockIdx.x * 256 + threadIdx.x;          // < 221184
  int e  = t & 7;
  int c  = (t >> 3) & 255;
  int q  = (t >> 11) & 3;
  int kc = t >> 13;
  int k  = kc * 32 + (q >> 1) * 16 + (q & 1) * 8 + e;
  qp[t] = f2bf(Q[c * 864 + k]);
}

// ---------------------------------------------------------------------------
// Kernel 3: fused Rad/Ysh build + on-the-fly-A GEMM.
// ---------------------------------------------------------------------------
#define RSTR 104   // Rad_s row stride (bf16): 208 B = 13*16B (bank-spread)

__global__ __launch_bounds__(256, 2)
void k_main(const float* __restrict__ r, const float* __restrict__ tbg,
            const unsigned int* __restrict__ ABt,
            const unsigned short* __restrict__ qp, const float* __restrict__ K0,
            float* __restrict__ out) {
  __shared__ unsigned short Rad_s[256][RSTR];  // 53248 B
  __shared__ float Ysh_s[256][9];              //  9216 B
  __shared__ unsigned short Qb[2][4096];       // 16384 B (2 x 8KB chunks)
  __shared__ float tb_s[128];                  //   512 B
  __shared__ float radii_s[256];               //  1024 B  -> total 80384 B

  const int tid  = threadIdx.x;
  const int lane = tid & 63;
  const int wave = tid >> 6;
  const int hl   = lane >> 5;
  const int l31  = lane & 31;
  const int zb   = blockIdx.x >> 1;
  const int cb   = blockIdx.x & 1;
  const int z0   = zb * 256;
  const char* qg = (const char*)qp;

  // stage Q chunk 0 (wave w stages sub-chunk q=w: 2048 B = 2 x 1024)
  {
    const char* g = qg + (size_t)wave * 4096 + cb * 2048 + lane * 16;
    char* l = ((char*)&Qb[0][0]) + wave * 2048;
    gl_lds16(g, l);
    gl_lds16(g + 1024, l + 1024);
  }
  if (tid < 128) tb_s[tid] = tbg[tid];

  // ---------------- phase 1: radii, Ysh, Rad (1 thread per row) ------------
  const int row = tid, z = z0 + row;
  {
    float rx = r[z * 3 + 0], ry = r[z * 3 + 1], rz = r[z * 3 + 2];
    float rad = sqrtf(rx * rx + ry * ry + rz * rz);
    radii_s[row] = rad;
    float inv = (rad > 0.f) ? (1.0f / rad) : 1.0f;
    float x = rx * inv, y = ry * inv, zc = rz * inv;
    const float SQ3 = 1.7320508075688772f, SQ5 = 2.2360679774997896f,
                SQ15 = 3.872983346207417f;
    Ysh_s[row][0] = 1.f;
    Ysh_s[row][1] = SQ3 * y;
    Ysh_s[row][2] = SQ3 * zc;
    Ysh_s[row][3] = SQ3 * x;
    Ysh_s[row][4] = SQ15 * x * y;
    Ysh_s[row][5] = SQ15 * y * zc;
    Ysh_s[row][6] = 0.5f * SQ5 * (3.f * zc * zc - 1.f);
    Ysh_s[row][7] = SQ15 * x * zc;
    Ysh_s[row][8] = 0.5f * SQ15 * (x * x - y * y);
    __syncthreads();   // tb_s ready (also drains chunk-0 stage; harmless)
    int lo = 0, hi = 128;
    while (lo < hi) { int mid = (lo + hi) >> 1;
                      if (tb_s[mid] < rad) lo = mid + 1; else hi = mid; }
    const uint4* abv = (const uint4*)(ABt + lo * 96);
#pragma unroll
    for (int gq = 0; gq < 12; ++gq) {
      uint4 u0 = abv[2 * gq], u1 = abv[2 * gq + 1];
      float r0 = fmaf(bf_lo(u0.x), rad, bf_hi(u0.x));
      float r1 = fmaf(bf_lo(u0.y), rad, bf_hi(u0.y));
      float r2 = fmaf(bf_lo(u0.z), rad, bf_hi(u0.z));
      float r3 = fmaf(bf_lo(u0.w), rad, bf_hi(u0.w));
      float r4 = fmaf(bf_lo(u1.x), rad, bf_hi(u1.x));
      float r5 = fmaf(bf_lo(u1.y), rad, bf_hi(u1.y));
      float r6 = fmaf(bf_lo(u1.z), rad, bf_hi(u1.z));
      float r7 = fmaf(bf_lo(u1.w), rad, bf_hi(u1.w));
      uint4 o;
      o.x = pack2(r0, r1); o.y = pack2(r2, r3);
      o.z = pack2(r4, r5); o.w = pack2(r6, r7);
      *(uint4*)(&Rad_s[row][gq * 8]) = o;
    }
  }
  __syncthreads();   // Rad_s / Ysh_s / radii_s ready

  // ---------------- phase 2: K-loop GEMM -----------------------------------
  const int row0 = wave * 64 + l31;
  const int row1 = row0 + 32;
  fx16 acc[2][4];
#pragma unroll
  for (int ri = 0; ri < 2; ++ri)
#pragma unroll
    for (int j = 0; j < 4; ++j)
#pragma unroll
      for (int e = 0; e < 16; ++e) acc[ri][j][e] = 0.f;

  int buf = 0;
  for (int kc = 0; kc < 27; ++kc) {
    if (kc + 1 < 27) {
      const char* g = qg + (size_t)((kc + 1) * 4 + wave) * 4096 + cb * 2048 + lane * 16;
      char* l = ((char*)&Qb[buf ^ 1][0]) + wave * 2048;
      gl_lds16(g, l);
      gl_lds16(g + 1024, l + 1024);
    }
    const int y  = kc / 3;
    const int wb = (kc - y * 3) * 32;
    const float Yv0 = Ysh_s[row0][y];
    const float Yv1 = Ysh_s[row1][y];
#pragma unroll
    for (int ks = 0; ks < 2; ++ks) {
      const int wo = wb + ks * 16 + hl * 8;
      uint4 u0 = *(const uint4*)(&Rad_s[row0][wo]);
      uint4 u1 = *(const uint4*)(&Rad_s[row1][wo]);
      uint4 p0, p1;
      p0.x = cvtpk(bf_lo(u0.x) * Yv0, bf_hi(u0.x) * Yv0);
      p0.y = cvtpk(bf_lo(u0.y) * Yv0, bf_hi(u0.y) * Yv0);
      p0.z = cvtpk(bf_lo(u0.z) * Yv0, bf_hi(u0.z) * Yv0);
      p0.w = cvtpk(bf_lo(u0.w) * Yv0, bf_hi(u0.w) * Yv0);
      p1.x = cvtpk(bf_lo(u1.x) * Yv1, bf_hi(u1.x) * Yv1);
      p1.y = cvtpk(bf_lo(u1.y) * Yv1, bf_hi(u1.y) * Yv1);
      p1.z = cvtpk(bf_lo(u1.z) * Yv1, bf_hi(u1.z) * Yv1);
      p1.w = cvtpk(bf_lo(u1.w) * Yv1, bf_hi(u1.w) * Yv1);
      union { uint4 u; bfrag f; } ua, ub;
      ua.u = p0; ub.u = p1;
      const bfrag a0 = ua.f, a1 = ub.f;
      const int qbase = (ks * 2 + hl) * 128;
#pragma unroll
      for (int j = 0; j < 4; ++j) {
        const bfrag b = *(const bfrag*)(&Qb[buf][(qbase + j * 32 + l31) * 8]);
        acc[0][j] = __builtin_amdgcn_mfma_f32_32x32x16_bf16(a0, b, acc[0][j], 0, 0, 0);
        acc[1][j] = __builtin_amdgcn_mfma_f32_32x32x16_bf16(a1, b, acc[1][j], 0, 0, 0);
      }
    }
    __syncthreads();
    buf ^= 1;
  }

  // ---------------- epilogue: mask-select vs K0, store ---------------------
  float k0v[4];
#pragma unroll
  for (int j = 0; j < 4; ++j) k0v[j] = K0[cb * 128 + j * 32 + l31];
  float radv[2][16];
#pragma unroll
  for (int ri = 0; ri < 2; ++ri)
#pragma unroll
    for (int rr = 0; rr < 16; ++rr)
      radv[ri][rr] = radii_s[wave * 64 + ri * 32 + (rr & 3) + 8 * (rr >> 2) + 4 * hl];
#pragma unroll
  for (int ri = 0; ri < 2; ++ri) {
#pragma unroll
    for (int rr = 0; rr < 16; ++rr) {
      const int rw = wave * 64 + ri * 32 + (rr & 3) + 8 * (rr >> 2) + 4 * hl;
      const bool m = radv[ri][rr] > 0.f;
      const size_t o = (size_t)(z0 + rw) * 256 + cb * 128 + l31;
#pragma unroll
      for (int j = 0; j < 4; ++j)
        out[o + j * 32] = m ? acc[ri][j][rr] : k0v[j];
    }
  }
}

// ---------------------------------------------------------------------------
extern "C" void kernel_launch(void* const* d_in, const int* in_sizes, int n_in,
                              void* d_out, int out_size, void* d_ws, size_t ws_size,
                              hipStream_t stream) {
  const float* r  = (const float*)d_in[0];
  const float* Q  = (const float*)d_in[1];
  const float* W1 = (const float*)d_in[2];
  const float* b1 = (const float*)d_in[3];
  const float* W2 = (const float*)d_in[4];
  const float* b2 = (const float*)d_in[5];
  const float* K0 = (const float*)d_in[6];
  float* out = (float*)d_out;
  char* ws = (char*)d_ws;
  float* tb = (float*)(ws + WS_TB);
  unsigned int* ABt = (unsigned int*)(ws + WS_ABT);
  unsigned short* qp = (unsigned short*)(ws + WS_QP);

  hipLaunchKernelGGL(k_tables, dim3(1), dim3(128), 0, stream, W1, b1, W2, b2, tb, ABt);
  hipLaunchKernelGGL(k_qpack, dim3(864), dim3(256), 0, stream, Q, qp);
  hipLaunchKernelGGL(k_main, dim3(512), dim3(256), 0, stream, r, tb, ABt, qp, K0, out);
}

// Round 3
// 74.108 us; speedup vs baseline: 1.7727x; 1.2815x over previous
//
#include <hip/hip_runtime.h>
#include <hip/hip_bf16.h>

// ---------------------------------------------------------------------------
// k1[z,i,j] = sum_{y,w} Q[i,j,y,w] * Ysh[z,y] * Rad[z,w]
//  => GEMM: P[z,k] @ Qmat[k,c], k = y*96+w (K=864), c = i*16+j (256)
// P rank-1 per row (P = Ysh[z,y]*Rad[z,w]) -> A-frags generated on the fly
// from LDS-resident Rad (bf16) + Ysh (f32).
// B (packed Q, 442 KB, L2-resident) is loaded DIRECTLY global->VGPR with a
// one-step register prefetch -> NO K-loop barriers, no LDS staging of Q.
// Rad(t) piecewise-linear in t=|r| -> bf16 (A,B) interval tables.
// ---------------------------------------------------------------------------

typedef __attribute__((ext_vector_type(8)))  short bfrag;   // 8 x bf16
typedef __attribute__((ext_vector_type(16))) float fx16;    // 32x32 accum

#define WS_TB  0        // 128 f32 sorted breakpoints (+inf pad)
#define WS_ABT 512      // 129*96 u32 (bf16 A | bf16 B<<16) = 49536 B
#define WS_QP  50048    // 27*2*256*2*8 bf16 = 442368 B packed Q
// total 492416 B

__device__ inline unsigned short f2bf(float f) {   // RNE float->bf16
  union { float f; unsigned int u; } v; v.f = f;
  unsigned int r = v.u + 0x7FFFu + ((v.u >> 16) & 1u);
  return (unsigned short)(r >> 16);
}
__device__ inline unsigned int pack2(float a, float b) {
  return (unsigned int)f2bf(a) | ((unsigned int)f2bf(b) << 16);
}
__device__ inline float bf_lo(unsigned int v) {
  union { unsigned int u; float f; } c; c.u = v << 16; return c.f;
}
__device__ inline float bf_hi(unsigned int v) {
  union { unsigned int u; float f; } c; c.u = v & 0xFFFF0000u; return c.f;
}
__device__ inline unsigned int cvtpk(float a, float b) {  // lo<-bf16(a), hi<-bf16(b)
  unsigned int d;
  asm("v_cvt_pk_bf16_f32 %0, %1, %2" : "=v"(d) : "v"(a), "v"(b));
  return d;
}

// ---------------------------------------------------------------------------
// Kernel 1 (fused prep): block 0 builds tables (W2 staged in LDS);
// blocks 1..864 repack Q -> bf16 layout [kc(27)][ks(2)][c(256)][hl(2)][e(8)],
// k = kc*32 + ks*16 + hl*8 + e. One B-frag load = contiguous 1KB per wave.
// ---------------------------------------------------------------------------
__global__ void k_prep(const float* __restrict__ Q,
                       const float* __restrict__ W1, const float* __restrict__ b1,
                       const float* __restrict__ W2, const float* __restrict__ b2,
                       float* __restrict__ tb, unsigned int* __restrict__ ABt,
                       unsigned short* __restrict__ qp) {
  const int tid = threadIdx.x;
  if (blockIdx.x != 0) {
    int t = (blockIdx.x - 1) * 256 + tid;          // < 221184
    int e  = t & 7;
    int hl = (t >> 3) & 1;
    int c  = (t >> 4) & 255;
    int ks = (t >> 12) & 1;
    int kc = t >> 13;
    int k  = kc * 32 + ks * 16 + hl * 8 + e;
    qp[t] = f2bf(Q[c * 864 + k]);
    return;
  }
  // ----- block 0: piecewise-linear tables -----
  __shared__ float w2_s[128 * 96];                 // 49152 B
  __shared__ float val_s[128], stb_s[128], w1_s[128], b1_s[128];
  __shared__ int   perm_s[128];
  for (int i = tid; i < 128 * 96; i += 256) w2_s[i] = W2[i];
  const float INF = __builtin_inff();
  if (tid < 128) {
    float w1 = W1[tid], b1v = b1[tid];
    w1_s[tid] = w1; b1_s[tid] = b1v;
    float tj = -b1v / w1;
    bool valid = (w1 != 0.0f) && (tj > 0.0f);
    val_s[tid] = valid ? tj : INF;
  }
  __syncthreads();
  if (tid < 128) {
    float v = val_s[tid];
    int rank = 0;
    for (int m = 0; m < 128; ++m) {
      float vm = val_s[m];
      rank += (vm < v || (vm == v && m < tid)) ? 1 : 0;
    }
    stb_s[rank] = v; perm_s[rank] = tid;
  }
  __syncthreads();
  if (tid < 128) tb[tid] = stb_s[tid];
  if (tid < 96) {
    float s0  = stb_s[0];
    float tm0 = (s0 == INF) ? 1.0f : 0.5f * s0;
    float sa = 0.f, sb = 0.f;
    for (int j = 0; j < 128; ++j) {
      if (tm0 * w1_s[j] + b1_s[j] > 0.0f) {
        float w2 = w2_s[j * 96 + tid];
        sa += w2 * w1_s[j]; sb += w2 * b1_s[j];
      }
    }
    float b2v = b2[tid];
    ABt[tid] = pack2(sa, sb + b2v);
    for (int s = 0; s < 128; ++s) {
      if (stb_s[s] < INF) {
        int j = perm_s[s];
        float w2 = w2_s[j * 96 + tid];
        if (w1_s[j] > 0.f) { sa += w2 * w1_s[j]; sb += w2 * b1_s[j]; }
        else               { sa -= w2 * w1_s[j]; sb -= w2 * b1_s[j]; }
      }
      ABt[(s + 1) * 96 + tid] = pack2(sa, sb + b2v);
    }
  }
}

// ---------------------------------------------------------------------------
// Kernel 2: fused Rad/Ysh build + barrier-free GEMM.
// Block = 256 rows x 128 cols, 4 waves (wave w: rows [w*64, w*64+64)),
// wave tile 64x128 = 2x4 frags of mfma_f32_32x32x16_bf16.
// B-frags direct from L2 (global_load_dwordx4), 1-step register prefetch.
// ---------------------------------------------------------------------------
#define RSTR 104   // Rad_s row stride (bf16): 208 B, conflict-free b128

__global__ __launch_bounds__(256, 2)
void k_main(const float* __restrict__ r, const float* __restrict__ tbg,
            const unsigned int* __restrict__ ABt,
            const unsigned short* __restrict__ qp, const float* __restrict__ K0,
            float* __restrict__ out) {
  __shared__ unsigned short Rad_s[256][RSTR];  // 53248 B
  __shared__ float Ysh_s[256][9];              //  9216 B
  __shared__ float tb_s[128];                  //   512 B
  __shared__ float radii_s[256];               //  1024 B -> 64000 B total

  const int tid  = threadIdx.x;
  const int lane = tid & 63;
  const int wave = tid >> 6;
  const int hl   = lane >> 5;
  const int l31  = lane & 31;
  const int zb   = blockIdx.x >> 1;
  const int cb   = blockIdx.x & 1;
  const int z0   = zb * 256;

  if (tid < 128) tb_s[tid] = tbg[tid];

  // ---------------- phase 1: radii, Ysh, Rad (1 thread per row) ------------
  const int row = tid, z = z0 + row;
  {
    float rx = r[z * 3 + 0], ry = r[z * 3 + 1], rz = r[z * 3 + 2];
    float rad = sqrtf(rx * rx + ry * ry + rz * rz);
    radii_s[row] = rad;
    float inv = (rad > 0.f) ? (1.0f / rad) : 1.0f;
    float x = rx * inv, y = ry * inv, zc = rz * inv;
    const float SQ3 = 1.7320508075688772f, SQ5 = 2.2360679774997896f,
                SQ15 = 3.872983346207417f;
    Ysh_s[row][0] = 1.f;
    Ysh_s[row][1] = SQ3 * y;
    Ysh_s[row][2] = SQ3 * zc;
    Ysh_s[row][3] = SQ3 * x;
    Ysh_s[row][4] = SQ15 * x * y;
    Ysh_s[row][5] = SQ15 * y * zc;
    Ysh_s[row][6] = 0.5f * SQ5 * (3.f * zc * zc - 1.f);
    Ysh_s[row][7] = SQ15 * x * zc;
    Ysh_s[row][8] = 0.5f * SQ15 * (x * x - y * y);
    __syncthreads();   // tb_s ready
    int lo = 0, hi = 128;
    while (lo < hi) { int mid = (lo + hi) >> 1;
                      if (tb_s[mid] < rad) lo = mid + 1; else hi = mid; }
    const uint4* abv = (const uint4*)(ABt + lo * 96);
#pragma unroll
    for (int gq = 0; gq < 12; ++gq) {
      uint4 u0 = abv[2 * gq], u1 = abv[2 * gq + 1];
      float r0 = fmaf(bf_lo(u0.x), rad, bf_hi(u0.x));
      float r1 = fmaf(bf_lo(u0.y), rad, bf_hi(u0.y));
      float r2 = fmaf(bf_lo(u0.z), rad, bf_hi(u0.z));
      float r3 = fmaf(bf_lo(u0.w), rad, bf_hi(u0.w));
      float r4 = fmaf(bf_lo(u1.x), rad, bf_hi(u1.x));
      float r5 = fmaf(bf_lo(u1.y), rad, bf_hi(u1.y));
      float r6 = fmaf(bf_lo(u1.z), rad, bf_hi(u1.z));
      float r7 = fmaf(bf_lo(u1.w), rad, bf_hi(u1.w));
      uint4 o;
      o.x = pack2(r0, r1); o.y = pack2(r2, r3);
      o.z = pack2(r4, r5); o.w = pack2(r6, r7);
      *(uint4*)(&Rad_s[row][gq * 8]) = o;
    }
  }
  __syncthreads();   // Rad_s / Ysh_s / radii_s ready — LAST barrier

  // ---------------- phase 2: barrier-free K-loop ---------------------------
  const int row0 = wave * 64 + l31;
  const int row1 = row0 + 32;
  fx16 acc[2][4];
#pragma unroll
  for (int ri = 0; ri < 2; ++ri)
#pragma unroll
    for (int j = 0; j < 4; ++j)
#pragma unroll
      for (int e = 0; e < 16; ++e) acc[ri][j][e] = 0.f;

  // per-lane B base: byte(kc,ks,j) = (kc*2+ks)*8192 + (cb*128+j*32+l31)*32 + hl*16
  const char* qb0 = (const char*)qp + (size_t)(cb * 128 + l31) * 32 + hl * 16;

  auto loadB = [&](uint4* dst, int kc, int ks) {
    const char* p = qb0 + (size_t)(kc * 2 + ks) * 8192;
    dst[0] = *(const uint4*)(p);
    dst[1] = *(const uint4*)(p + 1024);
    dst[2] = *(const uint4*)(p + 2048);
    dst[3] = *(const uint4*)(p + 3072);
  };
  auto agen = [&](int y, int wo, bfrag& a0, bfrag& a1) {
    const float Yv0 = Ysh_s[row0][y];
    const float Yv1 = Ysh_s[row1][y];
    uint4 u0 = *(const uint4*)(&Rad_s[row0][wo]);
    uint4 u1 = *(const uint4*)(&Rad_s[row1][wo]);
    uint4 p0, p1;
    p0.x = cvtpk(bf_lo(u0.x) * Yv0, bf_hi(u0.x) * Yv0);
    p0.y = cvtpk(bf_lo(u0.y) * Yv0, bf_hi(u0.y) * Yv0);
    p0.z = cvtpk(bf_lo(u0.z) * Yv0, bf_hi(u0.z) * Yv0);
    p0.w = cvtpk(bf_lo(u0.w) * Yv0, bf_hi(u0.w) * Yv0);
    p1.x = cvtpk(bf_lo(u1.x) * Yv1, bf_hi(u1.x) * Yv1);
    p1.y = cvtpk(bf_lo(u1.y) * Yv1, bf_hi(u1.y) * Yv1);
    p1.z = cvtpk(bf_lo(u1.z) * Yv1, bf_hi(u1.z) * Yv1);
    p1.w = cvtpk(bf_lo(u1.w) * Yv1, bf_hi(u1.w) * Yv1);
    union { uint4 u; bfrag f; } ua, ub;
    ua.u = p0; ub.u = p1;
    a0 = ua.f; a1 = ub.f;
  };

  uint4 curB[4], nxtB[4];
  loadB(curB, 0, 0);
  for (int kc = 0; kc < 27; ++kc) {
    const int y  = kc / 3;
    const int wb = (kc - y * 3) * 32;
    // ---- ks = 0: prefetch (kc,1), compute with curB ----
    loadB(nxtB, kc, 1);
    {
      bfrag a0, a1;
      agen(y, wb + hl * 8, a0, a1);
      union { uint4 u; bfrag f; } c0, c1, c2, c3;
      c0.u = curB[0]; c1.u = curB[1]; c2.u = curB[2]; c3.u = curB[3];
      acc[0][0] = __builtin_amdgcn_mfma_f32_32x32x16_bf16(a0, c0.f, acc[0][0], 0, 0, 0);
      acc[1][0] = __builtin_amdgcn_mfma_f32_32x32x16_bf16(a1, c0.f, acc[1][0], 0, 0, 0);
      acc[0][1] = __builtin_amdgcn_mfma_f32_32x32x16_bf16(a0, c1.f, acc[0][1], 0, 0, 0);
      acc[1][1] = __builtin_amdgcn_mfma_f32_32x32x16_bf16(a1, c1.f, acc[1][1], 0, 0, 0);
      acc[0][2] = __builtin_amdgcn_mfma_f32_32x32x16_bf16(a0, c2.f, acc[0][2], 0, 0, 0);
      acc[1][2] = __builtin_amdgcn_mfma_f32_32x32x16_bf16(a1, c2.f, acc[1][2], 0, 0, 0);
      acc[0][3] = __builtin_amdgcn_mfma_f32_32x32x16_bf16(a0, c3.f, acc[0][3], 0, 0, 0);
      acc[1][3] = __builtin_amdgcn_mfma_f32_32x32x16_bf16(a1, c3.f, acc[1][3], 0, 0, 0);
    }
    // ---- ks = 1: prefetch (kc+1,0), compute with nxtB ----
    if (kc + 1 < 27) loadB(curB, kc + 1, 0);
    {
      bfrag a0, a1;
      agen(y, wb + 16 + hl * 8, a0, a1);
      union { uint4 u; bfrag f; } c0, c1, c2, c3;
      c0.u = nxtB[0]; c1.u = nxtB[1]; c2.u = nxtB[2]; c3.u = nxtB[3];
      acc[0][0] = __builtin_amdgcn_mfma_f32_32x32x16_bf16(a0, c0.f, acc[0][0], 0, 0, 0);
      acc[1][0] = __builtin_amdgcn_mfma_f32_32x32x16_bf16(a1, c0.f, acc[1][0], 0, 0, 0);
      acc[0][1] = __builtin_amdgcn_mfma_f32_32x32x16_bf16(a0, c1.f, acc[0][1], 0, 0, 0);
      acc[1][1] = __builtin_amdgcn_mfma_f32_32x32x16_bf16(a1, c1.f, acc[1][1], 0, 0, 0);
      acc[0][2] = __builtin_amdgcn_mfma_f32_32x32x16_bf16(a0, c2.f, acc[0][2], 0, 0, 0);
      acc[1][2] = __builtin_amdgcn_mfma_f32_32x32x16_bf16(a1, c2.f, acc[1][2], 0, 0, 0);
      acc[0][3] = __builtin_amdgcn_mfma_f32_32x32x16_bf16(a0, c3.f, acc[0][3], 0, 0, 0);
      acc[1][3] = __builtin_amdgcn_mfma_f32_32x32x16_bf16(a1, c3.f, acc[1][3], 0, 0, 0);
    }
  }

  // ---------------- epilogue: mask-select vs K0, store ---------------------
  float k0v[4];
#pragma unroll
  for (int j = 0; j < 4; ++j) k0v[j] = K0[cb * 128 + j * 32 + l31];
#pragma unroll
  for (int ri = 0; ri < 2; ++ri) {
#pragma unroll
    for (int rr = 0; rr < 16; ++rr) {
      const int rw = wave * 64 + ri * 32 + (rr & 3) + 8 * (rr >> 2) + 4 * hl;
      const bool m = radii_s[rw] > 0.f;
      const size_t o = (size_t)(z0 + rw) * 256 + cb * 128 + l31;
#pragma unroll
      for (int j = 0; j < 4; ++j)
        out[o + j * 32] = m ? acc[ri][j][rr] : k0v[j];
    }
  }
}

// ---------------------------------------------------------------------------
extern "C" void kernel_launch(void* const* d_in, const int* in_sizes, int n_in,
                              void* d_out, int out_size, void* d_ws, size_t ws_size,
                              hipStream_t stream) {
  const float* r  = (const float*)d_in[0];
  const float* Q  = (const float*)d_in[1];
  const float* W1 = (const float*)d_in[2];
  const float* b1 = (const float*)d_in[3];
  const float* W2 = (const float*)d_in[4];
  const float* b2 = (const float*)d_in[5];
  const float* K0 = (const float*)d_in[6];
  float* out = (float*)d_out;
  char* ws = (char*)d_ws;
  float* tb = (float*)(ws + WS_TB);
  unsigned int* ABt = (unsigned int*)(ws + WS_ABT);
  unsigned short* qp = (unsigned short*)(ws + WS_QP);

  hipLaunchKernelGGL(k_prep, dim3(865), dim3(256), 0, stream,
                     Q, W1, b1, W2, b2, tb, ABt, qp);
  hipLaunchKernelGGL(k_main, dim3(512), dim3(256), 0, stream,
                     r, tb, ABt, qp, K0, out);
}

// Round 4
// 61.161 us; speedup vs baseline: 2.1480x; 1.2117x over previous
//
#include <hip/hip_runtime.h>
#include <hip/hip_bf16.h>

// ---------------------------------------------------------------------------
// k1[z,i,j] = sum_{y,w} Q[i,j,y,w] * Ysh[z,y] * Rad[z,w]
//  => GEMM: P[z,k] @ Qmat[k,c], k = y*96+w (K=864), c = i*16+j (256)
// Round-4 structure:
//  - K reordered as (wb-window, y): k = y*96 + wbi*32 + ks*16 + hl*8 + e.
//    Rad window [wb,wb+32) register-cached per wbi (4 ds_read_b128 / 9 phases);
//    Ysh[9] per row-pair cached in regs. No per-ks A LDS traffic.
//  - B staged in LDS (8KB/phase/block, double-buffered, global_load_lds 16B),
//    shared by all 4 waves -> L2 traffic /4. Conflict-free frag reads.
//  - 27 phases, one __syncthreads each; stage issued phase-early so the
//    barrier's vmcnt drain is hidden under ~1000 cyc of MFMA+VALU.
// Rad(t) piecewise-linear in t=|r| -> bf16 (A,B) interval tables.
// ---------------------------------------------------------------------------

typedef __attribute__((ext_vector_type(8)))  short bfrag;   // 8 x bf16
typedef __attribute__((ext_vector_type(16))) float fx16;    // 32x32 accum

#define WS_TB  0        // 128 f32 sorted breakpoints (+inf pad)
#define WS_ABT 512      // 129*96 u32 (bf16 A | bf16 B<<16) = 49536 B
#define WS_QP  50048    // 221184 bf16 = 442368 B packed Q
// total 492416 B

__device__ inline unsigned short f2bf(float f) {   // RNE float->bf16
  union { float f; unsigned int u; } v; v.f = f;
  unsigned int r = v.u + 0x7FFFu + ((v.u >> 16) & 1u);
  return (unsigned short)(r >> 16);
}
__device__ inline unsigned int pack2(float a, float b) {
  return (unsigned int)f2bf(a) | ((unsigned int)f2bf(b) << 16);
}
__device__ inline float bf_lo(unsigned int v) {
  union { unsigned int u; float f; } c; c.u = v << 16; return c.f;
}
__device__ inline float bf_hi(unsigned int v) {
  union { unsigned int u; float f; } c; c.u = v & 0xFFFF0000u; return c.f;
}
__device__ inline unsigned int cvtpk(float a, float b) {  // lo<-bf16(a), hi<-bf16(b)
  unsigned int d;
  asm("v_cvt_pk_bf16_f32 %0, %1, %2" : "=v"(d) : "v"(a), "v"(b));
  return d;
}

__device__ inline void gl_lds16(const void* g, void* l) {
  __builtin_amdgcn_global_load_lds(
      (const __attribute__((address_space(1))) unsigned int*)g,
      (__attribute__((address_space(3))) unsigned int*)l, 16, 0, 0);
}

// ---------------------------------------------------------------------------
// Kernel 1 (fused prep): block 0 builds tables (W2 LDS-staged, branch-free
// unrolled walk); blocks 1..108 repack Q.
// qp layout: [kcp(27)][cbf(2)][ks(2)][hl(2)][c128(128)][e(8)],
//   kcp = wbi*9 + y, c = cbf*128+c128, k = y*96 + wbi*32 + ks*16 + hl*8 + e.
// ---------------------------------------------------------------------------
__global__ void k_prep(const float* __restrict__ Q,
                       const float* __restrict__ W1, const float* __restrict__ b1,
                       const float* __restrict__ W2, const float* __restrict__ b2,
                       float* __restrict__ tb, unsigned int* __restrict__ ABt,
                       unsigned short* __restrict__ qp) {
  const int tid = threadIdx.x;
  if (blockIdx.x != 0) {
    int u = (blockIdx.x - 1) * 256 + tid;          // < 27648
    int c128 = u & 127;
    int hl   = (u >> 7) & 1;
    int ks   = (u >> 8) & 1;
    int cbf  = (u >> 9) & 1;
    int kcp  = u >> 10;                            // 0..26
    int wbi  = kcp / 9, y = kcp - wbi * 9;
    int c    = cbf * 128 + c128;
    int k    = y * 96 + wbi * 32 + ks * 16 + hl * 8;
    const float4* s = (const float4*)(Q + c * 864 + k);
    float4 a = s[0], b = s[1];
    uint4 o;
    o.x = pack2(a.x, a.y); o.y = pack2(a.z, a.w);
    o.z = pack2(b.x, b.y); o.w = pack2(b.z, b.w);
    *(uint4*)(qp + (size_t)u * 8) = o;
    return;
  }
  // ----- block 0: piecewise-linear tables -----
  __shared__ float w2_s[128 * 96];                 // 49152 B
  __shared__ float val_s[128], stb_s[128], w1_s[128], b1_s[128];
  __shared__ int   perm_s[128];
  for (int i = tid; i < 128 * 96; i += 256) w2_s[i] = W2[i];
  const float INF = __builtin_inff();
  if (tid < 128) {
    float w1 = W1[tid], b1v = b1[tid];
    w1_s[tid] = w1; b1_s[tid] = b1v;
    float tj = -b1v / w1;
    bool valid = (w1 != 0.0f) && (tj > 0.0f);
    val_s[tid] = valid ? tj : INF;
  }
  __syncthreads();
  if (tid < 128) {
    float v = val_s[tid];
    int rank = 0;
    for (int m = 0; m < 128; ++m) {
      float vm = val_s[m];
      rank += (vm < v || (vm == v && m < tid)) ? 1 : 0;
    }
    stb_s[rank] = v; perm_s[rank] = tid;
  }
  __syncthreads();
  if (tid < 128) tb[tid] = stb_s[tid];
  if (tid < 96) {
    float s0  = stb_s[0];
    float tm0 = (s0 == INF) ? 1.0f : 0.5f * s0;
    float sa = 0.f, sb = 0.f;
#pragma unroll 8
    for (int j = 0; j < 128; ++j) {
      float on = (tm0 * w1_s[j] + b1_s[j] > 0.0f) ? 1.f : 0.f;
      float w2 = on * w2_s[j * 96 + tid];
      sa += w2 * w1_s[j]; sb += w2 * b1_s[j];
    }
    float b2v = b2[tid];
    ABt[tid] = pack2(sa, sb + b2v);
    // branch-free unrolled breakpoint walk (loads pipeline across iters)
#pragma unroll 8
    for (int s = 0; s < 128; ++s) {
      int   j    = perm_s[s];
      float live = (stb_s[s] < INF) ? 1.f : 0.f;
      float sgn  = (w1_s[j] > 0.f) ? live : -live;
      float w2   = sgn * w2_s[j * 96 + tid];
      sa += w2 * w1_s[j]; sb += w2 * b1_s[j];
      ABt[(s + 1) * 96 + tid] = pack2(sa, sb + b2v);
    }
  }
}

// ---------------------------------------------------------------------------
// Kernel 2: fused Rad/Ysh build + GEMM, A register-windowed, B LDS-staged.
// Block = 256 rows x 128 cols, 4 waves (wave w: rows [w*64, w*64+64)),
// wave tile 64x128 = 2x4 frags of mfma_f32_32x32x16_bf16.
// ---------------------------------------------------------------------------
#define RSTR 104   // Rad_s row stride (elems): 208 B, 16B-aligned

__global__ __launch_bounds__(256, 2)
void k_main(const float* __restrict__ r, const float* __restrict__ tbg,
            const unsigned int* __restrict__ ABt,
            const unsigned short* __restrict__ qp, const float* __restrict__ K0,
            float* __restrict__ out) {
  __shared__ unsigned short Rad_s[256][RSTR];  // 53248 B
  __shared__ float Ysh_s[256][9];              //  9216 B
  __shared__ unsigned short Bb[2][4096];       // 16384 B (2 x 8KB phases)
  __shared__ float tb_s[128];                  //   512 B
  __shared__ float radii_s[256];               //  1024 B -> 80384 B total

  const int tid  = threadIdx.x;
  const int lane = tid & 63;
  const int wave = tid >> 6;
  const int hl   = lane >> 5;
  const int l31  = lane & 31;
  const int zb   = blockIdx.x >> 1;
  const int cb   = blockIdx.x & 1;
  const int z0   = zb * 256;
  const char* qg = (const char*)qp;

  // stage phase 0 into Bb[0] (in flight across phase 1)
  {
    const char* g = qg + (size_t)cb * 8192 + wave * 2048 + lane * 16;
    char* l = ((char*)&Bb[0][0]) + wave * 2048;
    gl_lds16(g, l);
    gl_lds16(g + 1024, l + 1024);
  }
  if (tid < 128) tb_s[tid] = tbg[tid];

  // ---------------- phase 1: radii, Ysh, Rad (1 thread per row) ------------
  const int row = tid, z = z0 + row;
  {
    float rx = r[z * 3 + 0], ry = r[z * 3 + 1], rz = r[z * 3 + 2];
    float rad = sqrtf(rx * rx + ry * ry + rz * rz);
    radii_s[row] = rad;
    float inv = (rad > 0.f) ? (1.0f / rad) : 1.0f;
    float x = rx * inv, y = ry * inv, zc = rz * inv;
    const float SQ3 = 1.7320508075688772f, SQ5 = 2.2360679774997896f,
                SQ15 = 3.872983346207417f;
    Ysh_s[row][0] = 1.f;
    Ysh_s[row][1] = SQ3 * y;
    Ysh_s[row][2] = SQ3 * zc;
    Ysh_s[row][3] = SQ3 * x;
    Ysh_s[row][4] = SQ15 * x * y;
    Ysh_s[row][5] = SQ15 * y * zc;
    Ysh_s[row][6] = 0.5f * SQ5 * (3.f * zc * zc - 1.f);
    Ysh_s[row][7] = SQ15 * x * zc;
    Ysh_s[row][8] = 0.5f * SQ15 * (x * x - y * y);
    __syncthreads();   // tb_s ready (drains stage(0) vmcnt early; harmless)
    int lo = 0, hi = 128;
    while (lo < hi) { int mid = (lo + hi) >> 1;
                      if (tb_s[mid] < rad) lo = mid + 1; else hi = mid; }
    const uint4* abv = (const uint4*)(ABt + lo * 96);
#pragma unroll
    for (int gq = 0; gq < 12; ++gq) {
      uint4 u0 = abv[2 * gq], u1 = abv[2 * gq + 1];
      float r0 = fmaf(bf_lo(u0.x), rad, bf_hi(u0.x));
      float r1 = fmaf(bf_lo(u0.y), rad, bf_hi(u0.y));
      float r2 = fmaf(bf_lo(u0.z), rad, bf_hi(u0.z));
      float r3 = fmaf(bf_lo(u0.w), rad, bf_hi(u0.w));
      float r4 = fmaf(bf_lo(u1.x), rad, bf_hi(u1.x));
      float r5 = fmaf(bf_lo(u1.y), rad, bf_hi(u1.y));
      float r6 = fmaf(bf_lo(u1.z), rad, bf_hi(u1.z));
      float r7 = fmaf(bf_lo(u1.w), rad, bf_hi(u1.w));
      uint4 o;
      o.x = pack2(r0, r1); o.y = pack2(r2, r3);
      o.z = pack2(r4, r5); o.w = pack2(r6, r7);
      *(uint4*)(&Rad_s[row][gq * 8]) = o;
    }
  }
  __syncthreads();   // Rad_s / Ysh_s / radii_s ready

  // ---------------- phase 2: K-loop, A in registers ------------------------
  const int row0 = wave * 64 + l31;
  const int row1 = row0 + 32;

  float ys0[9], ys1[9];
#pragma unroll
  for (int j = 0; j < 9; ++j) { ys0[j] = Ysh_s[row0][j]; ys1[j] = Ysh_s[row1][j]; }

  fx16 acc[2][4];
#pragma unroll
  for (int ri = 0; ri < 2; ++ri)
#pragma unroll
    for (int j = 0; j < 4; ++j)
#pragma unroll
      for (int e = 0; e < 16; ++e) acc[ri][j][e] = 0.f;

  // B frag byte offset inside a phase buffer: (ks*2+hl)*2048 + (j*32+l31)*16
  const int bfo = hl * 2048 + l31 * 16;

  for (int wbi = 0; wbi < 3; ++wbi) {
    const int wb = wbi * 32;
    // A window: rows row0,row1; halves at hl*8 within each 16-k slice
    const uint4 w00 = *(const uint4*)(&Rad_s[row0][wb + hl * 8]);
    const uint4 w01 = *(const uint4*)(&Rad_s[row0][wb + 16 + hl * 8]);
    const uint4 w10 = *(const uint4*)(&Rad_s[row1][wb + hl * 8]);
    const uint4 w11 = *(const uint4*)(&Rad_s[row1][wb + 16 + hl * 8]);
#pragma unroll
    for (int y = 0; y < 9; ++y) {
      const int p = wbi * 9 + y;
      if (p + 1 < 27) {   // stage next phase into the other buffer
        const char* g = qg + (size_t)((p + 1) * 2 + cb) * 8192 + wave * 2048 + lane * 16;
        char* l = ((char*)&Bb[(p + 1) & 1][0]) + wave * 2048;
        gl_lds16(g, l);
        gl_lds16(g + 1024, l + 1024);
      }
      const unsigned short* bbuf = &Bb[p & 1][0];
      const float Y0 = ys0[y], Y1 = ys1[y];
#pragma unroll
      for (int ks = 0; ks < 2; ++ks) {
        const uint4 u0 = ks ? w01 : w00;
        const uint4 u1 = ks ? w11 : w10;
        uint4 p0, p1;
        p0.x = cvtpk(bf_lo(u0.x) * Y0, bf_hi(u0.x) * Y0);
        p0.y = cvtpk(bf_lo(u0.y) * Y0, bf_hi(u0.y) * Y0);
        p0.z = cvtpk(bf_lo(u0.z) * Y0, bf_hi(u0.z) * Y0);
        p0.w = cvtpk(bf_lo(u0.w) * Y0, bf_hi(u0.w) * Y0);
        p1.x = cvtpk(bf_lo(u1.x) * Y1, bf_hi(u1.x) * Y1);
        p1.y = cvtpk(bf_lo(u1.y) * Y1, bf_hi(u1.y) * Y1);
        p1.z = cvtpk(bf_lo(u1.z) * Y1, bf_hi(u1.z) * Y1);
        p1.w = cvtpk(bf_lo(u1.w) * Y1, bf_hi(u1.w) * Y1);
        union { uint4 u; bfrag f; } ua, ub;
        ua.u = p0; ub.u = p1;
        const bfrag a0 = ua.f, a1 = ub.f;
        const char* bp = (const char*)bbuf + ks * 4096 + bfo;
#pragma unroll
        for (int j = 0; j < 4; ++j) {
          union { uint4 u; bfrag f; } bj;
          bj.u = *(const uint4*)(bp + j * 512);
          acc[0][j] = __builtin_amdgcn_mfma_f32_32x32x16_bf16(a0, bj.f, acc[0][j], 0, 0, 0);
          acc[1][j] = __builtin_amdgcn_mfma_f32_32x32x16_bf16(a1, bj.f, acc[1][j], 0, 0, 0);
        }
      }
      __syncthreads();   // readers done with Bb[p&1]; stage(p+1) drained
    }
  }

  // ---------------- epilogue: mask-select vs K0, store ---------------------
  float k0v[4];
#pragma unroll
  for (int j = 0; j < 4; ++j) k0v[j] = K0[cb * 128 + j * 32 + l31];
#pragma unroll
  for (int ri = 0; ri < 2; ++ri) {
#pragma unroll
    for (int rr = 0; rr < 16; ++rr) {
      const int rw = wave * 64 + ri * 32 + (rr & 3) + 8 * (rr >> 2) + 4 * hl;
      const bool m = radii_s[rw] > 0.f;
      const size_t o = (size_t)(z0 + rw) * 256 + cb * 128 + l31;
#pragma unroll
      for (int j = 0; j < 4; ++j)
        out[o + j * 32] = m ? acc[ri][j][rr] : k0v[j];
    }
  }
}

// ---------------------------------------------------------------------------
extern "C" void kernel_launch(void* const* d_in, const int* in_sizes, int n_in,
                              void* d_out, int out_size, void* d_ws, size_t ws_size,
                              hipStream_t stream) {
  const float* r  = (const float*)d_in[0];
  const float* Q  = (const float*)d_in[1];
  const float* W1 = (const float*)d_in[2];
  const float* b1 = (const float*)d_in[3];
  const float* W2 = (const float*)d_in[4];
  const float* b2 = (const float*)d_in[5];
  const float* K0 = (const float*)d_in[6];
  float* out = (float*)d_out;
  char* ws = (char*)d_ws;
  float* tb = (float*)(ws + WS_TB);
  unsigned int* ABt = (unsigned int*)(ws + WS_ABT);
  unsigned short* qp = (unsigned short*)(ws + WS_QP);

  hipLaunchKernelGGL(k_prep, dim3(109), dim3(256), 0, stream,
                     Q, W1, b1, W2, b2, tb, ABt, qp);
  hipLaunchKernelGGL(k_main, dim3(512), dim3(256), 0, stream,
                     r, tb, ABt, qp, K0, out);
}

// Round 5
// 57.335 us; speedup vs baseline: 2.2913x; 1.0667x over previous
//
#include <hip/hip_runtime.h>
#include <hip/hip_bf16.h>

// ---------------------------------------------------------------------------
// k1[z,i,j] = sum_{y,w} Q[i,j,y,w] * Ysh[z,y] * Rad[z,w]
//  => GEMM: P[z,k] @ Qmat[k,c], k = y*96+w (K=864), c = i*16+j (256)
// Round-5 structure (latency-bound fix: concurrency + pipeline depth):
//  - 8-wave blocks (512 thr), wave tile 32x128 (acc = 4 x fx16 = 64 AGPR).
//    16 waves/CU (4/SIMD). VGPR must stay <= 128 (launch_bounds(512,4)).
//  - Ysh per-lane in registers (recomputed from r, no LDS).
//  - B: 3-buffer LDS staging, stage(p+2) issued per phase, counted
//    s_waitcnt vmcnt(1) + raw s_barrier (T3/T4). 1 gl_lds16/wave/phase.
//  - A: Rad window register-cached per wbi (2 ds_read_b128 / 9 phases).
// Rad(t) piecewise-linear in t=|r| -> bf16 (A,B) interval tables.
// ---------------------------------------------------------------------------

typedef __attribute__((ext_vector_type(8)))  short bfrag;   // 8 x bf16
typedef __attribute__((ext_vector_type(16))) float fx16;    // 32x32 accum

#define WS_TB  0        // 128 f32 sorted breakpoints (+inf pad)
#define WS_ABT 512      // 129*96 u32 (bf16 A | bf16 B<<16) = 49536 B
#define WS_QP  50048    // 221184 bf16 = 442368 B packed Q
// total 492416 B

__device__ inline unsigned short f2bf(float f) {   // RNE float->bf16
  union { float f; unsigned int u; } v; v.f = f;
  unsigned int r = v.u + 0x7FFFu + ((v.u >> 16) & 1u);
  return (unsigned short)(r >> 16);
}
__device__ inline unsigned int pack2(float a, float b) {
  return (unsigned int)f2bf(a) | ((unsigned int)f2bf(b) << 16);
}
__device__ inline float bf_lo(unsigned int v) {
  union { unsigned int u; float f; } c; c.u = v << 16; return c.f;
}
__device__ inline float bf_hi(unsigned int v) {
  union { unsigned int u; float f; } c; c.u = v & 0xFFFF0000u; return c.f;
}
__device__ inline unsigned int cvtpk(float a, float b) {  // lo<-bf16(a), hi<-bf16(b)
  unsigned int d;
  asm("v_cvt_pk_bf16_f32 %0, %1, %2" : "=v"(d) : "v"(a), "v"(b));
  return d;
}
__device__ inline void gl_lds16(const void* g, void* l) {
  __builtin_amdgcn_global_load_lds(
      (const __attribute__((address_space(1))) unsigned int*)g,
      (__attribute__((address_space(3))) unsigned int*)l, 16, 0, 0);
}

// ---------------------------------------------------------------------------
// Kernel 1 (fused prep): block 0 builds tables; blocks 1..108 repack Q.
// qp layout (8-elem groups u): [kcp(27)][cbf(2)][ks(2)][hl(2)][c128(128)][e(8)]
//   kcp = wbi*9 + y, c = cbf*128+c128, k = y*96 + wbi*32 + ks*16 + hl*8 + e.
// ---------------------------------------------------------------------------
__global__ void k_prep(const float* __restrict__ Q,
                       const float* __restrict__ W1, const float* __restrict__ b1,
                       const float* __restrict__ W2, const float* __restrict__ b2,
                       float* __restrict__ tb, unsigned int* __restrict__ ABt,
                       unsigned short* __restrict__ qp) {
  const int tid = threadIdx.x;
  if (blockIdx.x != 0) {
    int u = (blockIdx.x - 1) * 256 + tid;          // < 27648
    int c128 = u & 127;
    int hl   = (u >> 7) & 1;
    int ks   = (u >> 8) & 1;
    int cbf  = (u >> 9) & 1;
    int kcp  = u >> 10;                            // 0..26
    int wbi  = kcp / 9, y = kcp - wbi * 9;
    int c    = cbf * 128 + c128;
    int k    = y * 96 + wbi * 32 + ks * 16 + hl * 8;
    const float4* s = (const float4*)(Q + c * 864 + k);
    float4 a = s[0], b = s[1];
    uint4 o;
    o.x = pack2(a.x, a.y); o.y = pack2(a.z, a.w);
    o.z = pack2(b.x, b.y); o.w = pack2(b.z, b.w);
    *(uint4*)(qp + (size_t)u * 8) = o;
    return;
  }
  // ----- block 0: piecewise-linear tables -----
  __shared__ float w2_s[128 * 96];                 // 49152 B
  __shared__ float val_s[128], stb_s[128], w1_s[128], b1_s[128];
  __shared__ int   perm_s[128];
  for (int i = tid; i < 128 * 96; i += 256) w2_s[i] = W2[i];
  const float INF = __builtin_inff();
  if (tid < 128) {
    float w1 = W1[tid], b1v = b1[tid];
    w1_s[tid] = w1; b1_s[tid] = b1v;
    float tj = -b1v / w1;
    bool valid = (w1 != 0.0f) && (tj > 0.0f);
    val_s[tid] = valid ? tj : INF;
  }
  __syncthreads();
  if (tid < 128) {
    float v = val_s[tid];
    int rank = 0;
    for (int m = 0; m < 128; ++m) {
      float vm = val_s[m];
      rank += (vm < v || (vm == v && m < tid)) ? 1 : 0;
    }
    stb_s[rank] = v; perm_s[rank] = tid;
  }
  __syncthreads();
  if (tid < 128) tb[tid] = stb_s[tid];
  if (tid < 96) {
    float s0  = stb_s[0];
    float tm0 = (s0 == INF) ? 1.0f : 0.5f * s0;
    float sa = 0.f, sb = 0.f;
#pragma unroll 8
    for (int j = 0; j < 128; ++j) {
      float on = (tm0 * w1_s[j] + b1_s[j] > 0.0f) ? 1.f : 0.f;
      float w2 = on * w2_s[j * 96 + tid];
      sa += w2 * w1_s[j]; sb += w2 * b1_s[j];
    }
    float b2v = b2[tid];
    ABt[tid] = pack2(sa, sb + b2v);
#pragma unroll 8
    for (int s = 0; s < 128; ++s) {
      int   j    = perm_s[s];
      float live = (stb_s[s] < INF) ? 1.f : 0.f;
      float sgn  = (w1_s[j] > 0.f) ? live : -live;
      float w2   = sgn * w2_s[j * 96 + tid];
      sa += w2 * w1_s[j]; sb += w2 * b1_s[j];
      ABt[(s + 1) * 96 + tid] = pack2(sa, sb + b2v);
    }
  }
}

// ---------------------------------------------------------------------------
// Kernel 2: fused build + GEMM. 512 thr = 8 waves, wave w rows [w*32,w*32+32),
// block covers 256 rows x 128 cols. 3-buffer counted-vmcnt B pipeline.
// ---------------------------------------------------------------------------
#define RSTR 104   // Rad_s row stride (elems): 208 B, 16B-aligned

__global__ __launch_bounds__(512, 4)
void k_main(const float* __restrict__ r, const float* __restrict__ tbg,
            const unsigned int* __restrict__ ABt,
            const unsigned short* __restrict__ qp, const float* __restrict__ K0,
            float* __restrict__ out) {
  __shared__ unsigned short Rad_s[256][RSTR];  // 53248 B
  __shared__ unsigned short Bb[3][4096];       // 24576 B (3 x 8KB phases)
  __shared__ float tb_s[128];                  //   512 B
  __shared__ float radii_s[256];               //  1024 B -> 79360 B total

  const int tid  = threadIdx.x;
  const int lane = tid & 63;
  const int wave = tid >> 6;                   // 0..7
  const int hl   = lane >> 5;
  const int l31  = lane & 31;
  const int zb   = blockIdx.x >> 1;
  const int cb   = blockIdx.x & 1;
  const int z0   = zb * 256;
  const char* qg = (const char*)qp;

  // ---- prologue: stage phases 0,1 (1 gl_lds16 = 1KB per wave per phase) ----
  {
    const char* g0 = qg + (size_t)cb * 8192 + wave * 1024 + lane * 16;
    gl_lds16(g0, ((char*)&Bb[0][0]) + wave * 1024);
    const char* g1 = qg + (size_t)(16384 + cb * 8192) + wave * 1024 + lane * 16;
    gl_lds16(g1, ((char*)&Bb[1][0]) + wave * 1024);
  }
  if (tid < 128) tb_s[tid] = tbg[tid];

  // ---- per-lane Ysh for this lane's GEMM row (register-resident) ----------
  const int myrow = wave * 32 + l31;
  float ys[9];
  {
    const float* rg = r + (size_t)(z0 + myrow) * 3;
    float rx = rg[0], ry = rg[1], rz = rg[2];
    float rad = sqrtf(rx * rx + ry * ry + rz * rz);
    float inv = (rad > 0.f) ? (1.0f / rad) : 1.0f;
    float x = rx * inv, y = ry * inv, zc = rz * inv;
    const float SQ3 = 1.7320508075688772f, SQ5 = 2.2360679774997896f,
                SQ15 = 3.872983346207417f;
    ys[0] = 1.f;
    ys[1] = SQ3 * y;  ys[2] = SQ3 * zc;  ys[3] = SQ3 * x;
    ys[4] = SQ15 * x * y;  ys[5] = SQ15 * y * zc;
    ys[6] = 0.5f * SQ5 * (3.f * zc * zc - 1.f);
    ys[7] = SQ15 * x * zc;
    ys[8] = 0.5f * SQ15 * (x * x - y * y);
  }

  // ---- phase 1: radii + Rad tile (2 threads per row) ----------------------
  {
    const int prow = tid >> 1, phalf = tid & 1;
    const float* rg = r + (size_t)(z0 + prow) * 3;
    float rx = rg[0], ry = rg[1], rz = rg[2];
    float rad = sqrtf(rx * rx + ry * ry + rz * rz);
    if (phalf == 0) radii_s[prow] = rad;
    __syncthreads();   // tb_s ready (drains prologue stages early; harmless)
    int lo = 0, hi = 128;
    while (lo < hi) { int mid = (lo + hi) >> 1;
                      if (tb_s[mid] < rad) lo = mid + 1; else hi = mid; }
    const uint4* abv = (const uint4*)(ABt + lo * 96 + phalf * 48);
    const int w0 = phalf * 48;
#pragma unroll
    for (int gq = 0; gq < 6; ++gq) {
      uint4 u0 = abv[2 * gq], u1 = abv[2 * gq + 1];
      float r0 = fmaf(bf_lo(u0.x), rad, bf_hi(u0.x));
      float r1 = fmaf(bf_lo(u0.y), rad, bf_hi(u0.y));
      float r2 = fmaf(bf_lo(u0.z), rad, bf_hi(u0.z));
      float r3 = fmaf(bf_lo(u0.w), rad, bf_hi(u0.w));
      float r4 = fmaf(bf_lo(u1.x), rad, bf_hi(u1.x));
      float r5 = fmaf(bf_lo(u1.y), rad, bf_hi(u1.y));
      float r6 = fmaf(bf_lo(u1.z), rad, bf_hi(u1.z));
      float r7 = fmaf(bf_lo(u1.w), rad, bf_hi(u1.w));
      uint4 o;
      o.x = pack2(r0, r1); o.y = pack2(r2, r3);
      o.z = pack2(r4, r5); o.w = pack2(r6, r7);
      *(uint4*)(&Rad_s[prow][w0 + gq * 8]) = o;
    }
  }
  asm volatile("s_waitcnt vmcnt(0) lgkmcnt(0)" ::: "memory");
  __builtin_amdgcn_s_barrier();          // Rad_s/radii_s/stage(0) published
  __builtin_amdgcn_sched_barrier(0);

  // ---- K-loop: 27 phases, 3-buffer counted-vmcnt pipeline -----------------
  fx16 acc[4];
#pragma unroll
  for (int j = 0; j < 4; ++j)
#pragma unroll
    for (int e = 0; e < 16; ++e) acc[j][e] = 0.f;

  const int bfo = hl * 2048 + l31 * 16;
  uint4 w00, w01;
#pragma unroll
  for (int p = 0; p < 27; ++p) {
    const int wbi = p / 9, y = p - wbi * 9;
    if (y == 0) {   // A-window for this wbi (row myrow, 32 w values)
      w00 = *(const uint4*)(&Rad_s[myrow][wbi * 32 + hl * 8]);
      w01 = *(const uint4*)(&Rad_s[myrow][wbi * 32 + 16 + hl * 8]);
    }
    if (p + 2 < 27) {   // stage phase p+2 into buf (p+2)%3
      const char* g = qg + (size_t)((p + 2) * 2 + cb) * 8192 + wave * 1024 + lane * 16;
      gl_lds16(g, ((char*)&Bb[(p + 2) % 3][0]) + wave * 1024);
    }
    const float Y0 = ys[y];
    const char* bbuf = (const char*)&Bb[p % 3][0];
#pragma unroll
    for (int ks = 0; ks < 2; ++ks) {
      const uint4 u0 = ks ? w01 : w00;
      uint4 pk;
      pk.x = cvtpk(bf_lo(u0.x) * Y0, bf_hi(u0.x) * Y0);
      pk.y = cvtpk(bf_lo(u0.y) * Y0, bf_hi(u0.y) * Y0);
      pk.z = cvtpk(bf_lo(u0.z) * Y0, bf_hi(u0.z) * Y0);
      pk.w = cvtpk(bf_lo(u0.w) * Y0, bf_hi(u0.w) * Y0);
      union { uint4 u; bfrag f; } ua; ua.u = pk;
      const char* bp = bbuf + ks * 4096 + bfo;
#pragma unroll
      for (int j = 0; j < 4; ++j) {
        union { uint4 u; bfrag f; } bj;
        bj.u = *(const uint4*)(bp + j * 512);
        acc[j] = __builtin_amdgcn_mfma_f32_32x32x16_bf16(ua.f, bj.f, acc[j], 0, 0, 0);
      }
    }
    // end-of-phase: retire stage(p+1) (keep stage(p+2) in flight), publish
    if (p + 2 < 27) {
      asm volatile("s_waitcnt vmcnt(1) lgkmcnt(0)" ::: "memory");
    } else if (p + 1 < 27) {
      asm volatile("s_waitcnt vmcnt(0) lgkmcnt(0)" ::: "memory");
    }
    if (p + 1 < 27) {
      __builtin_amdgcn_s_barrier();
      __builtin_amdgcn_sched_barrier(0);
    }
  }

  // ---- epilogue: mask-select vs K0, store ---------------------------------
  float k0v[4];
#pragma unroll
  for (int j = 0; j < 4; ++j) k0v[j] = K0[cb * 128 + j * 32 + l31];
#pragma unroll
  for (int rr = 0; rr < 16; ++rr) {
    const int rw = wave * 32 + (rr & 3) + 8 * (rr >> 2) + 4 * hl;
    const bool m = radii_s[rw] > 0.f;
    const size_t o = (size_t)(z0 + rw) * 256 + cb * 128 + l31;
#pragma unroll
    for (int j = 0; j < 4; ++j)
      out[o + j * 32] = m ? acc[j][rr] : k0v[j];
  }
}

// ---------------------------------------------------------------------------
extern "C" void kernel_launch(void* const* d_in, const int* in_sizes, int n_in,
                              void* d_out, int out_size, void* d_ws, size_t ws_size,
                              hipStream_t stream) {
  const float* r  = (const float*)d_in[0];
  const float* Q  = (const float*)d_in[1];
  const float* W1 = (const float*)d_in[2];
  const float* b1 = (const float*)d_in[3];
  const float* W2 = (const float*)d_in[4];
  const float* b2 = (const float*)d_in[5];
  const float* K0 = (const float*)d_in[6];
  float* out = (float*)d_out;
  char* ws = (char*)d_ws;
  float* tb = (float*)(ws + WS_TB);
  unsigned int* ABt = (unsigned int*)(ws + WS_ABT);
  unsigned short* qp = (unsigned short*)(ws + WS_QP);

  hipLaunchKernelGGL(k_prep, dim3(109), dim3(256), 0, stream,
                     Q, W1, b1, W2, b2, tb, ABt, qp);
  hipLaunchKernelGGL(k_main, dim3(512), dim3(512), 0, stream,
                     r, tb, ABt, qp, K0, out);
}